// Round 4
// baseline (492.570 us; speedup 1.0000x reference)
//
#include <hip/hip_runtime.h>
#include <stdint.h>

// h1[b,o] = sum_{i,j,k} t_i a_j v_k W1[o, i*97*97 + j*97 + k], t/a/v = [1, x].
// Tile T = o*97+i = contiguous 9409-float W span. k=1..96 contraction = K=96
// bf16 MFMA GEMM vs video; k=0 / j=0 / i=0 are the prepended-ones biases.
//
// R4: staging via async global_load_lds width=16 (coalesced, zero VALU, no
// in-wave vmcnt stalls — R3's 8x scalar loads at 32B lane-stride were 8x L1
// request amplification). Raw fp32 tile lands LINEARLY in LDS; a cheap
// LDS->LDS convert pass (bank-conflict-free: lanes j-consecutive, stride
// 97==1 mod 32) packs bf16 into the padded [97][104] MFMA layout. Single raw
// buffer + dbuf bf16 = 79 KB -> 2 persistent blocks/CU, grid = 512 exactly.
// i-fold in register, flush atomics only at o boundaries.

#define HID    96
#define NP1    97
#define ROWLEN 9409
#define BATCH  64
#define RSTR   104                  // bf16 LDS row stride (208 B, 16B-aligned)
#define NTILE  9312                 // 96*97
#define WTOTAL 87616608L            // 96*912673 floats in W1
#define NCHUNK 37                   // ceil(9412/256) 1KB DMA chunks per tile

typedef short bf16x8 __attribute__((ext_vector_type(8)));
typedef float f32x4  __attribute__((ext_vector_type(4)));
typedef const float __attribute__((address_space(1)))* gfp;
typedef float __attribute__((address_space(3)))* lfp;

__device__ __forceinline__ uint32_t pack2bf(float lo, float hi) {
    union { float f; uint32_t u; } a, b; a.f = lo; b.f = hi;
    uint32_t ra = (a.u + 0x7fffu + ((a.u >> 16) & 1u)) >> 16;          // RNE lo
    uint32_t rb = (b.u + 0x7fffu + ((b.u >> 16) & 1u)) & 0xffff0000u;  // RNE hi
    return ra | rb;
}

__global__ __launch_bounds__(256, 2)
void fusion_gemm(const float* __restrict__ W1,
                 const float* __restrict__ text_x,
                 const float* __restrict__ audio_x,
                 const float* __restrict__ video_x,
                 float* __restrict__ h1pre)   // [96][64], pre-zeroed
{
    __shared__ __align__(16) float Wraw[NCHUNK * 256];     // 37,888 B linear fp32
    __shared__ __align__(16) short Wbf[2][NP1 * RSTR];     // 2 x 20,176 B
    __shared__ float biasF[2][NP1];

    const int tid  = threadIdx.x;
    const int lane = tid & 63;
    const int wave = tid >> 6;
    const int quad = lane >> 4;
    const int col  = lane & 15;
    const int b    = wave * 16 + col;

    const int t0 = (int)(((long)blockIdx.x     * NTILE) >> 9);   // grid = 512
    const int t1 = (int)(((long)(blockIdx.x+1) * NTILE) >> 9);

    // ---- async DMA of tile T's raw span (linear, 1KB chunks, 16B/lane) ----
    auto dma_tile = [&](int T) {
        const long tb = (long)T * ROWLEN - (T & 3);        // 16B-aligned base
        for (int c = wave; c < NCHUNK; c += 4) {
            long gb = tb + c * 256;
            const float* g = W1 + gb + lane * 4;
            float* l = &Wraw[c * 256];                     // wave-uniform base
            if (gb + 256 <= WTOTAL) {
                __builtin_amdgcn_global_load_lds((gfp)g, (lfp)l, 16, 0, 0);
            } else {                                       // last chunk of last tile
                f32x4 v = (f32x4){0.f, 0.f, 0.f, 0.f};
                if (gb + lane * 4 + 4 <= WTOTAL) v = *(const f32x4*)g;
                *(f32x4*)&Wraw[c * 256 + lane * 4] = v;
            }
        }
    };

    // ---- LDS->LDS convert: raw fp32 (shifted linear) -> padded bf16 ----
    auto convert = [&](int T, int pbuf) {
        const int sh = T & 3;
        for (int j = tid; j < NP1; j += 256) biasF[pbuf][j] = Wraw[sh + j * NP1];
        for (int w = tid; w < NP1 * 12; w += 256) {
            int s = w / 97;                 // lanes j-consecutive: stride 97==1 mod 32
            int j = w - s * 97;
            const float* p = &Wraw[sh + j * NP1 + 1 + s * 8];
            uint4 q;
            q.x = pack2bf(p[0], p[1]);
            q.y = pack2bf(p[2], p[3]);
            q.z = pack2bf(p[4], p[5]);
            q.w = pack2bf(p[6], p[7]);
            *reinterpret_cast<uint4*>(&Wbf[pbuf][j * RSTR + s * 8]) = q;
        }
    };

    // ---- hoisted: video B-fragments (lane holds B[k=quad*8+e][n=col]) ----
    bf16x8 bfrag[3];
#pragma unroll
    for (int ks = 0; ks < 3; ++ks) {
        const float* vp = video_x + b * HID + ks * 32 + quad * 8;
        union { bf16x8 v; uint32_t d[4]; } u;
        u.d[0] = pack2bf(vp[0], vp[1]);
        u.d[1] = pack2bf(vp[2], vp[3]);
        u.d[2] = pack2bf(vp[4], vp[5]);
        u.d[3] = pack2bf(vp[6], vp[7]);
        bfrag[ks] = u.v;
    }

    // ---- hoisted: audio epilogue weights (D row j = quad*4 + r) ----
    float aval[28];
#pragma unroll
    for (int mt = 0; mt < 7; ++mt)
#pragma unroll
        for (int r = 0; r < 4; ++r) {
            int j = mt * 16 + quad * 4 + r;
            aval[mt * 4 + r] = (j == 0) ? 1.f
                             : (j <= 96 ? audio_x[b * HID + (j - 1)] : 0.f);
        }

    dma_tile(t0);
    __syncthreads();                 // raw(t0) ready
    convert(t0, 0);

    float sacc = 0.f;
    int p = 0;
    int ocur = t0 / 97;

    for (int T = t0; T < t1; ++T) {
        __syncthreads();             // convert(T) done; Wraw free; Wbf[p] ready
        if (T + 1 < t1) dma_tile(T + 1);

        // ---- MFMA: U[j,b] = sum_k W[j,1+k]*video[b,k]; 7 m-tiles ----
        f32x4 acc[7];
#pragma unroll
        for (int mt = 0; mt < 7; ++mt) acc[mt] = (f32x4){0.f, 0.f, 0.f, 0.f};
#pragma unroll
        for (int ks = 0; ks < 3; ++ks)
#pragma unroll
            for (int mt = 0; mt < 7; ++mt) {
                int j  = mt * 16 + col;
                int je = j > 96 ? 96 : j;            // clamped rows x0 in epilogue
                bf16x8 af = *reinterpret_cast<const bf16x8*>(
                    &Wbf[p][je * RSTR + ks * 32 + quad * 8]);
                acc[mt] = __builtin_amdgcn_mfma_f32_16x16x32_bf16(af, bfrag[ks], acc[mt], 0, 0, 0);
            }

        // ---- epilogue: S = sum_j a_j * (U[j,b] + W[j,0]);  x t_i fold ----
        float s = 0.f;
#pragma unroll
        for (int mt = 0; mt < 7; ++mt)
#pragma unroll
            for (int r = 0; r < 4; ++r) {
                int j  = mt * 16 + quad * 4 + r;
                int je = j > 96 ? 96 : j;
                s += (acc[mt][r] + biasF[p][je]) * aval[mt * 4 + r];
            }
        s += __shfl_xor(s, 16);
        s += __shfl_xor(s, 32);

        const int i = T - ocur * 97;
        float tw = (i == 0) ? 1.f : text_x[b * HID + (i - 1)];
        sacc += s * tw;

        // flush register i-fold at o boundary / range end
        bool last = (T + 1 == t1);
        if (last || (T + 1 == (ocur + 1) * 97)) {
            if (quad == 0) atomicAdd(&h1pre[ocur * BATCH + b], sacc);
            sacc = 0.f;
            ocur++;
        }

        if (!last) {
            __syncthreads();         // DMA(T+1) drained; Wbf[p^1] free
            convert(T + 1, p ^ 1);
            p ^= 1;
        }
    }
}

__global__ __launch_bounds__(64)
void mlp_tail(const float* __restrict__ h1pre, const float* __restrict__ b1,
              const float* __restrict__ W2, const float* __restrict__ b2,
              const float* __restrict__ W3, const float* __restrict__ b3,
              float* __restrict__ out)
{
    __shared__ float h1s[96];
    __shared__ float h2s[48];
    const int b = blockIdx.x;
    const int t = threadIdx.x;
    for (int o = t; o < 96; o += 64) {
        float v = h1pre[o * BATCH + b] + b1[o];
        h1s[o] = v > 0.f ? v : 0.f;
    }
    __syncthreads();
    if (t < 48) {
        float acc = b2[t];
#pragma unroll 8
        for (int o = 0; o < 96; ++o) acc += W2[t * 96 + o] * h1s[o];
        h2s[t] = acc > 0.f ? acc : 0.f;
    }
    __syncthreads();
    if (t < 3) {
        float acc = b3[t];
#pragma unroll
        for (int c = 0; c < 48; ++c) acc += W3[t * 48 + c] * h2s[c];
        out[b * 3 + t] = acc;
    }
}

extern "C" void kernel_launch(void* const* d_in, const int* in_sizes, int n_in,
                              void* d_out, int out_size, void* d_ws, size_t ws_size,
                              hipStream_t stream)
{
    const float* text  = (const float*)d_in[0];
    const float* audio = (const float*)d_in[1];
    const float* video = (const float*)d_in[2];
    const float* W1    = (const float*)d_in[3];
    const float* b1    = (const float*)d_in[4];
    const float* W2    = (const float*)d_in[5];
    const float* b2    = (const float*)d_in[6];
    const float* W3    = (const float*)d_in[7];
    const float* b3    = (const float*)d_in[8];
    float* h1pre = (float*)d_ws;

    hipMemsetAsync(h1pre, 0, HID * BATCH * sizeof(float), stream);
    fusion_gemm<<<512, 256, 0, stream>>>(W1, text, audio, video, h1pre);
    mlp_tail<<<BATCH, 64, 0, stream>>>(h1pre, b1, W2, b2, W3, b3, (float*)d_out);
}